// Round 1
// baseline (2184.027 us; speedup 1.0000x reference)
//
#include <hip/hip_runtime.h>

#define LRELU(x) ((x) > 0.f ? (x) : 0.01f * (x))

constexpr int C = 32;

// ---- degree + in-edge count per destination node ----
__global__ void k_deg_count(const int* __restrict__ col, const float* __restrict__ ea,
                            float* __restrict__ deg, int* __restrict__ cnt, int E) {
    int e = blockIdx.x * blockDim.x + threadIdx.x;
    if (e >= E) return;
    int c = col[e];
    atomicAdd(&deg[c], ea[e]);
    atomicAdd(&cnt[c], 1);
}

__global__ void k_dinv(const float* __restrict__ deg, float* __restrict__ dinv, int N) {
    int i = blockIdx.x * blockDim.x + threadIdx.x;
    if (i >= N) return;
    float d = deg[i];
    dinv[i] = d > 0.f ? rsqrtf(fmaxf(d, 1e-12f)) : 0.f;
}

// ---- exclusive scan of cnt -> rowptr (two-level) ----
__global__ void k_scan_block(const int* __restrict__ cnt, int* __restrict__ excl,
                             int* __restrict__ bsum, int N) {
    __shared__ int sm[256];
    int i = blockIdx.x * 256 + threadIdx.x;
    int v = (i < N) ? cnt[i] : 0;
    sm[threadIdx.x] = v;
    __syncthreads();
    for (int off = 1; off < 256; off <<= 1) {
        int t = (threadIdx.x >= off) ? sm[threadIdx.x - off] : 0;
        __syncthreads();
        sm[threadIdx.x] += t;
        __syncthreads();
    }
    if (i < N) excl[i] = sm[threadIdx.x] - v;
    if (threadIdx.x == 255) bsum[blockIdx.x] = sm[255];
}

__global__ void k_scan_bsum(int* __restrict__ bsum, int nb) {
    __shared__ int sm[1024];
    for (int i = threadIdx.x; i < nb; i += blockDim.x) sm[i] = bsum[i];
    __syncthreads();
    if (threadIdx.x == 0) {
        int run = 0;
        for (int i = 0; i < nb; ++i) { int v = sm[i]; sm[i] = run; run += v; }
    }
    __syncthreads();
    for (int i = threadIdx.x; i < nb; i += blockDim.x) bsum[i] = sm[i];
}

__global__ void k_scan_add(int* __restrict__ rowptr, const int* __restrict__ bsum,
                           int* __restrict__ cursor, int N, int E) {
    int i = blockIdx.x * 256 + threadIdx.x;
    if (i < N) {
        int v = rowptr[i] + bsum[blockIdx.x];
        rowptr[i] = v;
        cursor[i] = v;
    }
    if (i == 0) rowptr[N] = E;
}

// ---- CSR fill: bucket edges by destination, weight = dinv[row]*ea*dinv[col] ----
__global__ void k_fill(const int* __restrict__ row, const int* __restrict__ col,
                       const float* __restrict__ ea, const float* __restrict__ dinv,
                       int* __restrict__ cursor, int* __restrict__ csrc,
                       float* __restrict__ cw, int E) {
    int e = blockIdx.x * blockDim.x + threadIdx.x;
    if (e >= E) return;
    int r = row[e], c = col[e];
    float w = dinv[r] * ea[e] * dinv[c];
    int p = atomicAdd(&cursor[c], 1);
    csrc[p] = r;
    cw[p] = w;
}

// ---- read-in MLP: h = lrelu([state,action] @ W_in + b_in) ----
__global__ void k_inmlp(const float* __restrict__ state, const float* __restrict__ action,
                        const float* __restrict__ Win, const float* __restrict__ bin,
                        float* __restrict__ h, int N) {
    int t = blockIdx.x * blockDim.x + threadIdx.x;
    int i = t >> 5, c = t & 31;
    if (i >= N) return;
    float acc = bin[c];
#pragma unroll
    for (int d = 0; d < 8; ++d) acc += state[i * 8 + d] * Win[d * 32 + c];
#pragma unroll
    for (int d = 0; d < 2; ++d) acc += action[i * 2 + d] * Win[(8 + d) * 32 + c];
    h[i * 32 + c] = LRELU(acc);
}

// ---- out (+)= z @ W  (32x32), optional bias init, optional lrelu->h on last tap ----
__global__ void k_tapmm(const float* __restrict__ z, const float* __restrict__ W,
                        const float* __restrict__ bias, float* __restrict__ out,
                        float* __restrict__ hdst, int N, int init, int act) {
    int t = blockIdx.x * blockDim.x + threadIdx.x;
    int i = t >> 5, c = t & 31;
    if (i >= N) return;
    float zc = z[i * 32 + c];
    float acc = init ? bias[c] : out[i * 32 + c];
#pragma unroll
    for (int j = 0; j < 32; ++j) {
        float zj = __shfl(zc, j, 32);
        acc += zj * W[j * 32 + c];
    }
    if (act) hdst[i * 32 + c] = LRELU(acc);
    else out[i * 32 + c] = acc;
}

// ---- propagate: zout[i][c] = sum_{e in CSR[i]} w[e] * zin[src[e]][c] ----
__global__ void k_propagate(const int* __restrict__ rowptr, const int* __restrict__ src,
                            const float* __restrict__ w, const float* __restrict__ zin,
                            float* __restrict__ zout, int N) {
    int t = blockIdx.x * blockDim.x + threadIdx.x;
    int g = t >> 5, c = t & 31;
    if (g >= N) return;
    int s = rowptr[g], e = rowptr[g + 1];
    float acc = 0.f;
    for (int base = s; base < e; base += 32) {
        int m = e - base; if (m > 32) m = 32;
        int sv = 0; float wv = 0.f;
        if (c < m) { sv = src[base + c]; wv = w[base + c]; }
        for (int t2 = 0; t2 < m; ++t2) {
            int ss = __shfl(sv, t2, 32);
            float ww = __shfl(wv, t2, 32);
            acc += ww * zin[ss * 32 + c];
        }
    }
    zout[g * 32 + c] = acc;
}

// ---- readout: y=h@W_out+b_out, scatter-mean by batch ----
__global__ void k_readout(const float* __restrict__ h, const float* __restrict__ Wout,
                          const float* __restrict__ bout, const int* __restrict__ batch,
                          float* __restrict__ sums, float* __restrict__ cntf, int N) {
    int t = blockIdx.x * blockDim.x + threadIdx.x;
    int i = t >> 5, c = t & 31;
    if (i >= N) return;
    float v = h[i * 32 + c] * Wout[c];
#pragma unroll
    for (int off = 16; off; off >>= 1) v += __shfl_xor(v, off, 32);
    if (c == 0) {
        int b = batch[i];
        atomicAdd(&sums[b], v + bout[0]);
        atomicAdd(&cntf[b], 1.0f);
    }
}

__global__ void k_final(const float* __restrict__ sums, const float* __restrict__ cntf,
                        float* __restrict__ out, int B) {
    int b = blockIdx.x * blockDim.x + threadIdx.x;
    if (b >= B) return;
    out[b] = sums[b] / fmaxf(cntf[b], 1.0f);
}

static inline size_t algn(size_t x) { return (x + 255) & ~(size_t)255; }

extern "C" void kernel_launch(void* const* d_in, const int* in_sizes, int n_in,
                              void* d_out, int out_size, void* d_ws, size_t ws_size,
                              hipStream_t stream) {
    const float* state  = (const float*)d_in[0];
    const float* action = (const float*)d_in[1];
    const int*   eidx   = (const int*)d_in[2];
    const float* eattr  = (const float*)d_in[3];
    const int*   batch  = (const int*)d_in[4];
    const float* Win    = (const float*)d_in[5];
    const float* bin    = (const float*)d_in[6];
    const float* Wtaps  = (const float*)d_in[7];
    const float* bgnn   = (const float*)d_in[8];
    const float* Wout   = (const float*)d_in[9];
    const float* bout   = (const float*)d_in[10];
    float* out = (float*)d_out;

    const int N = in_sizes[0] / 8;       // SD=8
    const int E = in_sizes[3];
    const int B = out_size;              // [B,1]
    const int K = 4, L = 2;
    const int nb = (N + 255) / 256;

    const int* row = eidx;
    const int* col = eidx + E;

    // ---- workspace layout ----
    char* base = (char*)d_ws;
    float* deg  = (float*)base;
    int*   cntN = (int*)(deg + N);
    float* sums = (float*)(cntN + N);
    float* cntf = sums + B;
    size_t zbytes = (size_t)(2 * N + 2 * B) * 4;
    char* p = base + algn(zbytes);
    float* dinv   = (float*)p; p += algn((size_t)N * 4);
    int*   rowptr = (int*)p;   p += algn((size_t)(N + 1) * 4);
    int*   cursor = (int*)p;   p += algn((size_t)N * 4);
    int*   bsum   = (int*)p;   p += algn((size_t)nb * 4);
    int*   csrc   = (int*)p;   p += algn((size_t)E * 4);
    float* cw     = (float*)p; p += algn((size_t)E * 4);
    float* h      = (float*)p; p += algn((size_t)N * C * 4);
    float* zA     = (float*)p; p += algn((size_t)N * C * 4);
    float* zB     = (float*)p; p += algn((size_t)N * C * 4);
    float* outacc = (float*)p; p += algn((size_t)N * C * 4);
    (void)ws_size; (void)n_in;

    const int BT = 256;
    const int gE  = (E + BT - 1) / BT;
    const int gN  = (N + BT - 1) / BT;
    const int gNC = ((size_t)N * 32 + BT - 1) / BT;

    hipMemsetAsync(d_ws, 0, zbytes, stream);

    k_deg_count<<<gE, BT, 0, stream>>>(col, eattr, deg, cntN, E);
    k_dinv<<<gN, BT, 0, stream>>>(deg, dinv, N);
    k_scan_block<<<nb, 256, 0, stream>>>(cntN, rowptr, bsum, N);
    k_scan_bsum<<<1, 1024, 0, stream>>>(bsum, nb);
    k_scan_add<<<nb, 256, 0, stream>>>(rowptr, bsum, cursor, N, E);
    k_fill<<<gE, BT, 0, stream>>>(row, col, eattr, dinv, cursor, csrc, cw, E);

    k_inmlp<<<gNC, BT, 0, stream>>>(state, action, Win, bin, h, N);

    for (int l = 0; l < L; ++l) {
        const float* Wl = Wtaps + (size_t)l * (K + 1) * 32 * 32;
        const float* bl = bgnn + (size_t)l * 32;
        // tap 0: out = h @ W0 + b
        k_tapmm<<<gNC, BT, 0, stream>>>(h, Wl, bl, outacc, h, N, 1, 0);
        const float* zcur = h;
        for (int k = 1; k <= K; ++k) {
            float* znext = (k & 1) ? zA : zB;
            k_propagate<<<gNC, BT, 0, stream>>>(rowptr, csrc, cw, zcur, znext, N);
            int act = (k == K) ? 1 : 0;
            k_tapmm<<<gNC, BT, 0, stream>>>(znext, Wl + (size_t)k * 32 * 32, nullptr,
                                            outacc, h, N, 0, act);
            zcur = znext;
        }
    }

    k_readout<<<gNC, BT, 0, stream>>>(h, Wout, bout, batch, sums, cntf, N);
    k_final<<<(B + BT - 1) / BT, BT, 0, stream>>>(sums, cntf, out, B);
}

// Round 2
// 2114.723 us; speedup vs baseline: 1.0328x; 1.0328x over previous
//
#include <hip/hip_runtime.h>

#define LRELU(x) ((x) > 0.f ? (x) : 0.01f * (x))

constexpr int C = 32;

// ---- degree + in-edge count per destination node ----
__global__ void k_deg_count(const int* __restrict__ col, const float* __restrict__ ea,
                            float* __restrict__ deg, int* __restrict__ cnt, int E) {
    int e = blockIdx.x * blockDim.x + threadIdx.x;
    if (e >= E) return;
    int c = col[e];
    atomicAdd(&deg[c], ea[e]);
    atomicAdd(&cnt[c], 1);
}

__global__ void k_dinv(const float* __restrict__ deg, float* __restrict__ dinv, int N) {
    int i = blockIdx.x * blockDim.x + threadIdx.x;
    if (i >= N) return;
    float d = deg[i];
    dinv[i] = d > 0.f ? rsqrtf(fmaxf(d, 1e-12f)) : 0.f;
}

// ---- exclusive scan of cnt -> rowptr (two-level) ----
__global__ void k_scan_block(const int* __restrict__ cnt, int* __restrict__ excl,
                             int* __restrict__ bsum, int N) {
    __shared__ int sm[256];
    int i = blockIdx.x * 256 + threadIdx.x;
    int v = (i < N) ? cnt[i] : 0;
    sm[threadIdx.x] = v;
    __syncthreads();
    for (int off = 1; off < 256; off <<= 1) {
        int t = (threadIdx.x >= off) ? sm[threadIdx.x - off] : 0;
        __syncthreads();
        sm[threadIdx.x] += t;
        __syncthreads();
    }
    if (i < N) excl[i] = sm[threadIdx.x] - v;
    if (threadIdx.x == 255) bsum[blockIdx.x] = sm[255];
}

__global__ void k_scan_bsum(int* __restrict__ bsum, int nb) {
    __shared__ int sm[1024];
    for (int i = threadIdx.x; i < nb; i += blockDim.x) sm[i] = bsum[i];
    __syncthreads();
    if (threadIdx.x == 0) {
        int run = 0;
        for (int i = 0; i < nb; ++i) { int v = sm[i]; sm[i] = run; run += v; }
    }
    __syncthreads();
    for (int i = threadIdx.x; i < nb; i += blockDim.x) bsum[i] = sm[i];
}

__global__ void k_scan_add(int* __restrict__ rowptr, const int* __restrict__ bsum,
                           int* __restrict__ cursor, int N, int E) {
    int i = blockIdx.x * 256 + threadIdx.x;
    if (i < N) {
        int v = rowptr[i] + bsum[blockIdx.x];
        rowptr[i] = v;
        cursor[i] = v;
    }
    if (i == 0) rowptr[N] = E;
}

// ---- CSR fill: bucket edges by destination, weight = dinv[row]*ea*dinv[col] ----
__global__ void k_fill(const int* __restrict__ row, const int* __restrict__ col,
                       const float* __restrict__ ea, const float* __restrict__ dinv,
                       int* __restrict__ cursor, int* __restrict__ csrc,
                       float* __restrict__ cw, int E) {
    int e = blockIdx.x * blockDim.x + threadIdx.x;
    if (e >= E) return;
    int r = row[e], c = col[e];
    float w = dinv[r] * ea[e] * dinv[c];
    int p = atomicAdd(&cursor[c], 1);
    csrc[p] = r;
    cw[p] = w;
}

// ---- read-in MLP: h = lrelu([state,action] @ W_in + b_in) ----
__global__ void k_inmlp(const float* __restrict__ state, const float* __restrict__ action,
                        const float* __restrict__ Win, const float* __restrict__ bin,
                        float* __restrict__ h, int N) {
    int t = blockIdx.x * blockDim.x + threadIdx.x;
    int i = t >> 5, c = t & 31;
    if (i >= N) return;
    float acc = bin[c];
#pragma unroll
    for (int d = 0; d < 8; ++d) acc += state[i * 8 + d] * Win[d * 32 + c];
#pragma unroll
    for (int d = 0; d < 2; ++d) acc += action[i * 2 + d] * Win[(8 + d) * 32 + c];
    h[i * 32 + c] = LRELU(acc);
}

// ---- fused tap: znext = propagate(zin); outacc (+)= [tap0] + znext@Wk; tail fusions ----
// first: acc = bias + zin_own @ W0 + znext @ W1   (k==1)
// mid:   acc = outacc + znext @ Wk; write znext, outacc
// last:  h = lrelu(acc); write h, or (readout) y[g] = h . Wout + bout
__global__ void k_tap(const int* __restrict__ rowptr, const int* __restrict__ src,
                      const float* __restrict__ w, const float* __restrict__ zin,
                      float* __restrict__ znext, float* __restrict__ outacc,
                      const float* __restrict__ Wl, int k, const float* __restrict__ bias,
                      float* __restrict__ hout, float* __restrict__ yout,
                      const float* __restrict__ Wout, const float* __restrict__ bout,
                      int N, int first, int last, int readout) {
    int t = blockIdx.x * blockDim.x + threadIdx.x;
    int g = t >> 5, c = t & 31;
    if (g >= N) return;
    // propagate: z = sum_e w[e] * zin[src[e]][c]
    int s = rowptr[g], e = rowptr[g + 1];
    float z = 0.f;
    for (int base = s; base < e; base += 32) {
        int m = e - base; if (m > 32) m = 32;
        int sv = 0; float wv = 0.f;
        if (c < m) { sv = src[base + c]; wv = w[base + c]; }
        for (int t2 = 0; t2 < m; ++t2) {
            int ss = __shfl(sv, t2, 32);
            float ww = __shfl(wv, t2, 32);
            z += ww * zin[ss * 32 + c];
        }
    }
    const float* Wk = Wl + (size_t)k * 32 * 32;
    float acc;
    if (first) {
        float hown = zin[g * 32 + c];
        acc = bias[c];
#pragma unroll
        for (int j = 0; j < 32; ++j) acc += __shfl(hown, j, 32) * Wl[j * 32 + c];
    } else {
        acc = outacc[g * 32 + c];
    }
#pragma unroll
    for (int j = 0; j < 32; ++j) acc += __shfl(z, j, 32) * Wk[j * 32 + c];
    if (!last) {
        znext[g * 32 + c] = z;
        outacc[g * 32 + c] = acc;
    } else {
        float hv = LRELU(acc);
        if (!readout) {
            hout[g * 32 + c] = hv;
        } else {
            float v = hv * Wout[c];
#pragma unroll
            for (int off = 16; off; off >>= 1) v += __shfl_xor(v, off, 32);
            if (c == 0) yout[g] = v + bout[0];
        }
    }
}

// ---- segmented mean over sorted batch: one block per graph ----
__global__ void k_segmean(const float* __restrict__ y, const int* __restrict__ batch,
                          float* __restrict__ out, int N) {
    int b = blockIdx.x;
    __shared__ int slo, shi;
    if (threadIdx.x == 0) {
        int lo = 0, hi = N;
        while (lo < hi) { int m = (lo + hi) >> 1; if (batch[m] < b) lo = m + 1; else hi = m; }
        slo = lo;
        hi = N;
        while (lo < hi) { int m = (lo + hi) >> 1; if (batch[m] < b + 1) lo = m + 1; else hi = m; }
        shi = lo;
    }
    __syncthreads();
    int lo = slo, hi = shi;
    float sum = 0.f;
    for (int i = lo + threadIdx.x; i < hi; i += blockDim.x) sum += y[i];
    __shared__ float sm[256];
    sm[threadIdx.x] = sum;
    __syncthreads();
    for (int o = 128; o; o >>= 1) {
        if (threadIdx.x < o) sm[threadIdx.x] += sm[threadIdx.x + o];
        __syncthreads();
    }
    if (threadIdx.x == 0) out[b] = sm[0] / fmaxf((float)(hi - lo), 1.0f);
}

static inline size_t algn(size_t x) { return (x + 255) & ~(size_t)255; }

extern "C" void kernel_launch(void* const* d_in, const int* in_sizes, int n_in,
                              void* d_out, int out_size, void* d_ws, size_t ws_size,
                              hipStream_t stream) {
    const float* state  = (const float*)d_in[0];
    const float* action = (const float*)d_in[1];
    const int*   eidx   = (const int*)d_in[2];
    const float* eattr  = (const float*)d_in[3];
    const int*   batch  = (const int*)d_in[4];
    const float* Win    = (const float*)d_in[5];
    const float* bin    = (const float*)d_in[6];
    const float* Wtaps  = (const float*)d_in[7];
    const float* bgnn   = (const float*)d_in[8];
    const float* Wout   = (const float*)d_in[9];
    const float* bout   = (const float*)d_in[10];
    float* out = (float*)d_out;

    const int N = in_sizes[0] / 8;       // SD=8
    const int E = in_sizes[3];
    const int B = out_size;              // [B,1]
    const int K = 4, L = 2;
    const int nb = (N + 255) / 256;

    const int* row = eidx;
    const int* col = eidx + E;

    // ---- workspace layout ----
    char* base = (char*)d_ws;
    float* deg  = (float*)base;
    int*   cntN = (int*)(deg + N);
    size_t zbytes = (size_t)(2 * N) * 4;            // deg + cnt zeroed
    char* p = base + algn(zbytes);
    float* dinv   = (float*)p; p += algn((size_t)N * 4);
    int*   rowptr = (int*)p;   p += algn((size_t)(N + 1) * 4);
    int*   cursor = (int*)p;   p += algn((size_t)N * 4);
    int*   bsum   = (int*)p;   p += algn((size_t)nb * 4);
    int*   csrc   = (int*)p;   p += algn((size_t)E * 4);
    float* cw     = (float*)p; p += algn((size_t)E * 4);
    float* h      = (float*)p; p += algn((size_t)N * C * 4);
    float* zA     = (float*)p; p += algn((size_t)N * C * 4);
    float* zB     = (float*)p; p += algn((size_t)N * C * 4);
    float* outacc = (float*)p; p += algn((size_t)N * C * 4);
    float* yv     = (float*)p; p += algn((size_t)N * 4);
    (void)ws_size; (void)n_in;

    const int BT = 256;
    const int gE  = (E + BT - 1) / BT;
    const int gN  = (N + BT - 1) / BT;
    const int gNC = ((size_t)N * 32 + BT - 1) / BT;

    hipMemsetAsync(d_ws, 0, zbytes, stream);

    k_deg_count<<<gE, BT, 0, stream>>>(col, eattr, deg, cntN, E);
    k_dinv<<<gN, BT, 0, stream>>>(deg, dinv, N);
    k_scan_block<<<nb, 256, 0, stream>>>(cntN, rowptr, bsum, N);
    k_scan_bsum<<<1, 1024, 0, stream>>>(bsum, nb);
    k_scan_add<<<nb, 256, 0, stream>>>(rowptr, bsum, cursor, N, E);
    k_fill<<<gE, BT, 0, stream>>>(row, col, eattr, dinv, cursor, csrc, cw, E);

    k_inmlp<<<gNC, BT, 0, stream>>>(state, action, Win, bin, h, N);

    for (int l = 0; l < L; ++l) {
        const float* Wl = Wtaps + (size_t)l * (K + 1) * 32 * 32;
        const float* bl = bgnn + (size_t)l * 32;
        const float* zcur = h;
        for (int k = 1; k <= K; ++k) {
            float* znext = (k & 1) ? zA : zB;
            int first = (k == 1);
            int last  = (k == K);
            int rdout = last && (l == L - 1);
            k_tap<<<gNC, BT, 0, stream>>>(rowptr, csrc, cw, zcur, znext, outacc,
                                          Wl, k, bl, h, yv, Wout, bout,
                                          N, first, last, rdout);
            zcur = znext;
        }
    }

    k_segmean<<<B, 256, 0, stream>>>(yv, batch, out, N);
}

// Round 3
// 1350.351 us; speedup vs baseline: 1.6174x; 1.5661x over previous
//
#include <hip/hip_runtime.h>

#define LRELU(x) ((x) > 0.f ? (x) : 0.01f * (x))

constexpr int C = 32;

// ---- packed 16-bit histogram of edge destinations ----
__global__ void k_hist(const int* __restrict__ col, unsigned* __restrict__ hist, int E) {
    int e = blockIdx.x * blockDim.x + threadIdx.x;
    if (e >= E) return;
    int c = col[e];
    atomicAdd(&hist[c >> 1], 1u << ((c & 1) * 16));
}

// ---- exclusive scan of packed counts -> rowptr (two-level) ----
__global__ void k_scan_block(const unsigned* __restrict__ hist, int* __restrict__ excl,
                             int* __restrict__ bsum, int N) {
    __shared__ int sm[256];
    int i = blockIdx.x * 256 + threadIdx.x;
    int v = 0;
    if (i < N) v = (hist[i >> 1] >> ((i & 1) * 16)) & 0xffff;
    sm[threadIdx.x] = v;
    __syncthreads();
    for (int off = 1; off < 256; off <<= 1) {
        int t = (threadIdx.x >= off) ? sm[threadIdx.x - off] : 0;
        __syncthreads();
        sm[threadIdx.x] += t;
        __syncthreads();
    }
    if (i < N) excl[i] = sm[threadIdx.x] - v;
    if (threadIdx.x == 255) bsum[blockIdx.x] = sm[255];
}

__global__ void k_scan_bsum(int* __restrict__ bsum, int nb) {
    __shared__ int sm[1024];
    for (int i = threadIdx.x; i < nb; i += blockDim.x) sm[i] = bsum[i];
    __syncthreads();
    if (threadIdx.x == 0) {
        int run = 0;
        for (int i = 0; i < nb; ++i) { int v = sm[i]; sm[i] = run; run += v; }
    }
    __syncthreads();
    for (int i = threadIdx.x; i < nb; i += blockDim.x) bsum[i] = sm[i];
}

__global__ void k_scan_add(int* __restrict__ rowptr, const int* __restrict__ bsum,
                           int N, int E) {
    int i = blockIdx.x * 256 + threadIdx.x;
    if (i < N) rowptr[i] += bsum[blockIdx.x];
    if (i == 0) rowptr[N] = E;
}

// ---- CSR fill: pair {src, ea_bits}, slot = rowptr[dst] + packed-16 local cursor ----
__global__ void k_fill(const int* __restrict__ row, const int* __restrict__ col,
                       const float* __restrict__ ea, const int* __restrict__ rowptr,
                       unsigned* __restrict__ cur, int2* __restrict__ pairs, int E) {
    int e = blockIdx.x * blockDim.x + threadIdx.x;
    if (e >= E) return;
    int r = row[e], c = col[e];
    int sh = (c & 1) * 16;
    unsigned old = atomicAdd(&cur[c >> 1], 1u << sh);
    int local = (old >> sh) & 0xffff;
    int p = rowptr[c] + local;
    pairs[p] = make_int2(r, __float_as_int(ea[e]));
}

// ---- deg = segmented (coalesced) sum of ea over CSR row; dinv = rsqrt ----
__global__ void k_degdinv(const int* __restrict__ rowptr, const int2* __restrict__ pairs,
                          float* __restrict__ dinv, int N) {
    int t = blockIdx.x * blockDim.x + threadIdx.x;
    int g = t >> 5, c = t & 31;
    if (g >= N) return;
    int s = rowptr[g], e = rowptr[g + 1];
    float d = 0.f;
    for (int p = s + c; p < e; p += 32) d += __int_as_float(pairs[p].y);
#pragma unroll
    for (int off = 16; off; off >>= 1) d += __shfl_xor(d, off, 32);
    if (c == 0) dinv[g] = d > 0.f ? rsqrtf(fmaxf(d, 1e-12f)) : 0.f;
}

// ---- read-in MLP: h = lrelu([state,action]@W_in+b_in); v = dinv*h ----
__global__ void k_inmlp(const float* __restrict__ state, const float* __restrict__ action,
                        const float* __restrict__ Win, const float* __restrict__ bin,
                        const float* __restrict__ dinv,
                        float* __restrict__ h, float* __restrict__ v, int N) {
    int t = blockIdx.x * blockDim.x + threadIdx.x;
    int i = t >> 5, c = t & 31;
    if (i >= N) return;
    float acc = bin[c];
#pragma unroll
    for (int d = 0; d < 8; ++d) acc += state[i * 8 + d] * Win[d * 32 + c];
#pragma unroll
    for (int d = 0; d < 2; ++d) acc += action[i * 2 + d] * Win[(8 + d) * 32 + c];
    float hv = LRELU(acc);
    h[i * 32 + c] = hv;
    v[i * 32 + c] = dinv[i] * hv;
}

// ---- fused tap in v-space ----
// t = sum_e ea_e * vin[src_e];  z = dinv[g]*t;  vout = dinv[g]*z
// first: acc = bias + hin@W0 + z@W1 ; mid: acc = outacc + z@Wk
// last(!readout): h=lrelu(acc), vout=dinv*h ; last(readout): y[g]=h.Wout+bout
__global__ void k_tap(const int* __restrict__ rowptr, const int2* __restrict__ pairs,
                      const float* __restrict__ vin, const float* __restrict__ hin,
                      const float* __restrict__ dinv,
                      float* __restrict__ outacc, float* __restrict__ vout,
                      float* __restrict__ hout, float* __restrict__ yout,
                      const float* __restrict__ Wl, int k, const float* __restrict__ bias,
                      const float* __restrict__ Wout, const float* __restrict__ bout,
                      int N, int first, int last, int readout) {
    int tt = blockIdx.x * blockDim.x + threadIdx.x;
    int g = tt >> 5, c = tt & 31;
    if (g >= N) return;
    int s = rowptr[g], e = rowptr[g + 1];
    float t = 0.f;
#pragma unroll 4
    for (int p = s; p < e; ++p) {
        int2 pr = pairs[p];                    // uniform 8B load per group
        t += __int_as_float(pr.y) * vin[(size_t)pr.x * 32 + c];  // coalesced gather
    }
    float di = dinv[g];
    float z = di * t;
    const float* Wk = Wl + (size_t)k * 32 * 32;
    float acc;
    if (first) {
        float hown = hin[g * 32 + c];
        acc = bias[c];
#pragma unroll
        for (int j = 0; j < 32; ++j) acc += __shfl(hown, j, 32) * Wl[j * 32 + c];
    } else {
        acc = outacc[g * 32 + c];
    }
#pragma unroll
    for (int j = 0; j < 32; ++j) acc += __shfl(z, j, 32) * Wk[j * 32 + c];
    if (!last) {
        vout[g * 32 + c] = di * z;             // = dinv^2 * t
        outacc[g * 32 + c] = acc;
    } else {
        float hv = LRELU(acc);
        if (!readout) {
            hout[g * 32 + c] = hv;
            vout[g * 32 + c] = di * hv;        // v_0 for next layer
        } else {
            float v = hv * Wout[c];
#pragma unroll
            for (int off = 16; off; off >>= 1) v += __shfl_xor(v, off, 32);
            if (c == 0) yout[g] = v + bout[0];
        }
    }
}

// ---- segmented mean over sorted batch: one block per graph ----
__global__ void k_segmean(const float* __restrict__ y, const int* __restrict__ batch,
                          float* __restrict__ out, int N) {
    int b = blockIdx.x;
    __shared__ int slo, shi;
    if (threadIdx.x == 0) {
        int lo = 0, hi = N;
        while (lo < hi) { int m = (lo + hi) >> 1; if (batch[m] < b) lo = m + 1; else hi = m; }
        slo = lo;
        hi = N;
        while (lo < hi) { int m = (lo + hi) >> 1; if (batch[m] < b + 1) lo = m + 1; else hi = m; }
        shi = lo;
    }
    __syncthreads();
    int lo = slo, hi = shi;
    float sum = 0.f;
    for (int i = lo + threadIdx.x; i < hi; i += blockDim.x) sum += y[i];
    __shared__ float sm[256];
    sm[threadIdx.x] = sum;
    __syncthreads();
    for (int o = 128; o; o >>= 1) {
        if (threadIdx.x < o) sm[threadIdx.x] += sm[threadIdx.x + o];
        __syncthreads();
    }
    if (threadIdx.x == 0) out[b] = sm[0] / fmaxf((float)(hi - lo), 1.0f);
}

static inline size_t algn(size_t x) { return (x + 255) & ~(size_t)255; }

extern "C" void kernel_launch(void* const* d_in, const int* in_sizes, int n_in,
                              void* d_out, int out_size, void* d_ws, size_t ws_size,
                              hipStream_t stream) {
    const float* state  = (const float*)d_in[0];
    const float* action = (const float*)d_in[1];
    const int*   eidx   = (const int*)d_in[2];
    const float* eattr  = (const float*)d_in[3];
    const int*   batch  = (const int*)d_in[4];
    const float* Win    = (const float*)d_in[5];
    const float* bin    = (const float*)d_in[6];
    const float* Wtaps  = (const float*)d_in[7];
    const float* bgnn   = (const float*)d_in[8];
    const float* Wout   = (const float*)d_in[9];
    const float* bout   = (const float*)d_in[10];
    float* out = (float*)d_out;

    const int N = in_sizes[0] / 8;       // SD=8
    const int E = in_sizes[3];
    const int B = out_size;
    const int K = 4, L = 2;
    const int nb = (N + 255) / 256;
    const int Nw = (N + 1) >> 1;         // packed 16-bit words

    const int* row = eidx;
    const int* col = eidx + E;

    // ---- workspace layout ----
    char* base = (char*)d_ws;
    unsigned* hist = (unsigned*)base;            // Nw words, zeroed
    unsigned* cur  = hist + Nw;                  // Nw words, zeroed
    size_t zbytes = (size_t)(2 * Nw) * 4;
    char* p = base + algn(zbytes);
    float* dinv   = (float*)p; p += algn((size_t)N * 4);
    int*   rowptr = (int*)p;   p += algn((size_t)(N + 1) * 4);
    int*   bsum   = (int*)p;   p += algn((size_t)nb * 4);
    int2*  pairs  = (int2*)p;  p += algn((size_t)E * 8);
    float* h      = (float*)p; p += algn((size_t)N * C * 4);
    float* vh     = (float*)p; p += algn((size_t)N * C * 4);
    float* vA     = (float*)p; p += algn((size_t)N * C * 4);
    float* vB     = (float*)p; p += algn((size_t)N * C * 4);
    float* outacc = (float*)p; p += algn((size_t)N * C * 4);
    float* yv     = (float*)p; p += algn((size_t)N * 4);
    (void)ws_size; (void)n_in;

    const int BT = 256;
    const int gE  = (E + BT - 1) / BT;
    const int gNC = ((size_t)N * 32 + BT - 1) / BT;

    hipMemsetAsync(d_ws, 0, zbytes, stream);

    k_hist<<<gE, BT, 0, stream>>>(col, hist, E);
    k_scan_block<<<nb, 256, 0, stream>>>(hist, rowptr, bsum, N);
    k_scan_bsum<<<1, 1024, 0, stream>>>(bsum, nb);
    k_scan_add<<<nb, 256, 0, stream>>>(rowptr, bsum, N, E);
    k_fill<<<gE, BT, 0, stream>>>(row, col, eattr, rowptr, cur, pairs, E);
    k_degdinv<<<gNC, BT, 0, stream>>>(rowptr, pairs, dinv, N);
    k_inmlp<<<gNC, BT, 0, stream>>>(state, action, Win, bin, dinv, h, vh, N);

    for (int l = 0; l < L; ++l) {
        const float* Wl = Wtaps + (size_t)l * (K + 1) * 32 * 32;
        const float* bl = bgnn + (size_t)l * 32;
        const float* vin = vh;
        for (int k = 1; k <= K; ++k) {
            int first = (k == 1);
            int last  = (k == K);
            int rdout = last && (l == L - 1);
            float* vout = last ? vh : ((k & 1) ? vA : vB);
            k_tap<<<gNC, BT, 0, stream>>>(rowptr, pairs, vin, h, dinv,
                                          outacc, vout, h, yv,
                                          Wl, k, bl, Wout, bout,
                                          N, first, last, rdout);
            vin = vout;
        }
    }

    k_segmean<<<B, 256, 0, stream>>>(yv, batch, out, N);
}

// Round 4
// 694.707 us; speedup vs baseline: 3.1438x; 1.9438x over previous
//
#include <hip/hip_runtime.h>

#define LRELU(x) ((x) > 0.f ? (x) : 0.01f * (x))

constexpr int C = 32;
constexpr int BSH = 7;            // 128 dst-nodes per bucket
constexpr int MAXBK = 1024;       // max buckets (N <= 131072)

// ---- bucket histogram (LDS-privatized) ----
__global__ void k_bhist(const int* __restrict__ col, int* __restrict__ ghist, int E) {
    __shared__ int lh[MAXBK];
    for (int i = threadIdx.x; i < MAXBK; i += blockDim.x) lh[i] = 0;
    __syncthreads();
    int chunk = (E + gridDim.x - 1) / gridDim.x;
    int c0 = blockIdx.x * chunk, c1 = min(E, c0 + chunk);
    for (int e = c0 + threadIdx.x; e < c1; e += blockDim.x)
        atomicAdd(&lh[col[e] >> BSH], 1);
    __syncthreads();
    for (int i = threadIdx.x; i < MAXBK; i += blockDim.x) {
        int v = lh[i];
        if (v) atomicAdd(&ghist[i], v);
    }
}

// ---- exclusive scan of bucket counts -> bbase, gcur ----
__global__ void k_bscan(const int* __restrict__ ghist, int* __restrict__ bbase,
                        int* __restrict__ gcur, int nbk, int E) {
    __shared__ int sm[1024];
    int tid = threadIdx.x;
    int v = (tid < nbk) ? ghist[tid] : 0;
    sm[tid] = v;
    __syncthreads();
    for (int off = 1; off < 1024; off <<= 1) {
        int t = (tid >= off) ? sm[tid - off] : 0;
        __syncthreads();
        sm[tid] += t;
        __syncthreads();
    }
    if (tid < nbk) {
        int excl = sm[tid] - v;
        bbase[tid] = excl;
        gcur[tid] = excl;
    }
    if (tid == 0) bbase[nbk] = E;
}

// ---- partition edges into buckets; per-wg claimed contiguous runs ----
// tmp entry: { src | (dstLow7 << 17), ea_bits }
__global__ void k_part(const int* __restrict__ row, const int* __restrict__ col,
                       const float* __restrict__ ea, int* __restrict__ gcur,
                       int2* __restrict__ tmp, int E) {
    __shared__ int lcnt[MAXBK];
    __shared__ int lbase[MAXBK];
    __shared__ int lcur[MAXBK];
    for (int i = threadIdx.x; i < MAXBK; i += blockDim.x) { lcnt[i] = 0; lcur[i] = 0; }
    __syncthreads();
    int chunk = (E + gridDim.x - 1) / gridDim.x;
    int c0 = blockIdx.x * chunk, c1 = min(E, c0 + chunk);
    for (int e = c0 + threadIdx.x; e < c1; e += blockDim.x)
        atomicAdd(&lcnt[col[e] >> BSH], 1);
    __syncthreads();
    for (int b = threadIdx.x; b < MAXBK; b += blockDim.x) {
        int c = lcnt[b];
        lbase[b] = c ? atomicAdd(&gcur[b], c) : 0;
    }
    __syncthreads();
    for (int e = c0 + threadIdx.x; e < c1; e += blockDim.x) {
        int cc = col[e];
        int b = cc >> BSH;
        int r = atomicAdd(&lcur[b], 1);
        tmp[lbase[b] + r] = make_int2(row[e] | ((cc & 127) << 17), __float_as_int(ea[e]));
    }
}

// ---- per-bucket: node counts + deg (LDS), scan -> rowptr/dinv, scatter to CSR ----
__global__ void k_build(const int* __restrict__ bbase, const int2* __restrict__ tmp,
                        int* __restrict__ rowptr, float* __restrict__ dinv,
                        int2* __restrict__ pairs, int N, int E) {
    __shared__ int ncnt[128], noff[128], ncur[128], scn[128];
    __shared__ float ndeg[128];
    int tid = threadIdx.x;
    int bg = blockIdx.x;
    int node0 = bg << BSH;
    int s = bbase[bg], e = bbase[bg + 1];
    if (tid < 128) { ncnt[tid] = 0; ncur[tid] = 0; ndeg[tid] = 0.f; }
    __syncthreads();
    for (int p = s + tid; p < e; p += blockDim.x) {
        int2 u = tmp[p];
        int nl = (u.x >> 17) & 127;
        atomicAdd(&ncnt[nl], 1);
        atomicAdd(&ndeg[nl], __int_as_float(u.y));
    }
    __syncthreads();
    int v = 0;
    if (tid < 128) { v = ncnt[tid]; scn[tid] = v; }
    __syncthreads();
    for (int off = 1; off < 128; off <<= 1) {
        int t = 0;
        if (tid < 128 && tid >= off) t = scn[tid - off];
        __syncthreads();
        if (tid < 128) scn[tid] += t;
        __syncthreads();
    }
    if (tid < 128) {
        int excl = scn[tid] - v;
        noff[tid] = excl;
        int node = node0 + tid;
        if (node < N) {
            rowptr[node] = s + excl;
            float d = ndeg[tid];
            dinv[node] = d > 0.f ? rsqrtf(fmaxf(d, 1e-12f)) : 0.f;
        }
    }
    if (bg == gridDim.x - 1 && tid == 0) rowptr[N] = E;
    __syncthreads();
    for (int p = s + tid; p < e; p += blockDim.x) {
        int2 u = tmp[p];
        int nl = (u.x >> 17) & 127;
        int r = atomicAdd(&ncur[nl], 1);
        pairs[s + noff[nl] + r] = make_int2(u.x & 0x1FFFF, u.y);
    }
}

// ---- read-in MLP: h = lrelu([state,action]@W_in+b_in); v = dinv*h ----
__global__ void k_inmlp(const float* __restrict__ state, const float* __restrict__ action,
                        const float* __restrict__ Win, const float* __restrict__ bin,
                        const float* __restrict__ dinv,
                        float* __restrict__ h, float* __restrict__ v, int N) {
    int t = blockIdx.x * blockDim.x + threadIdx.x;
    int i = t >> 5, c = t & 31;
    if (i >= N) return;
    float acc = bin[c];
#pragma unroll
    for (int d = 0; d < 8; ++d) acc += state[i * 8 + d] * Win[d * 32 + c];
#pragma unroll
    for (int d = 0; d < 2; ++d) acc += action[i * 2 + d] * Win[(8 + d) * 32 + c];
    float hv = LRELU(acc);
    h[i * 32 + c] = hv;
    v[i * 32 + c] = dinv[i] * hv;
}

// acc(4 cols) += z(row, spread over 8 lanes as float4) @ W(32x32), cols 4q..4q+3
__device__ __forceinline__ void mm_acc(float4& acc, float4 zq,
                                       const float* __restrict__ W, int q) {
#pragma unroll
    for (int a = 0; a < 8; ++a) {
        float z0 = __shfl(zq.x, a, 8), z1 = __shfl(zq.y, a, 8);
        float z2 = __shfl(zq.z, a, 8), z3 = __shfl(zq.w, a, 8);
        const float4 w0 = *(const float4*)&W[(4 * a + 0) * 32 + 4 * q];
        const float4 w1 = *(const float4*)&W[(4 * a + 1) * 32 + 4 * q];
        const float4 w2 = *(const float4*)&W[(4 * a + 2) * 32 + 4 * q];
        const float4 w3 = *(const float4*)&W[(4 * a + 3) * 32 + 4 * q];
        acc.x += z0 * w0.x + z1 * w1.x + z2 * w2.x + z3 * w3.x;
        acc.y += z0 * w0.y + z1 * w1.y + z2 * w2.y + z3 * w3.y;
        acc.z += z0 * w0.z + z1 * w1.z + z2 * w2.z + z3 * w3.z;
        acc.w += z0 * w0.w + z1 * w1.w + z2 * w2.w + z3 * w3.w;
    }
}

// ---- fused tap in v-space; 8 lanes per node, float4 per lane ----
__global__ void k_tap4(const int* __restrict__ rowptr, const int2* __restrict__ pairs,
                       const float* __restrict__ vin, const float* __restrict__ hin,
                       const float* __restrict__ dinv,
                       float* __restrict__ outacc, float* __restrict__ vout,
                       float* __restrict__ hout, float* __restrict__ yout,
                       const float* __restrict__ Wl, int k, const float* __restrict__ bias,
                       const float* __restrict__ Wout, const float* __restrict__ bout,
                       int N, int first, int last, int readout) {
    int t = blockIdx.x * blockDim.x + threadIdx.x;
    int g = t >> 3, q = t & 7;
    if (g >= N) return;
    int s = rowptr[g], e = rowptr[g + 1];
    float4 tv = {0.f, 0.f, 0.f, 0.f};
#pragma unroll 4
    for (int p = s; p < e; ++p) {
        int2 pr = pairs[p];
        float w = __int_as_float(pr.y);
        const float4* vp = (const float4*)(vin + ((size_t)pr.x << 5));
        float4 x = vp[q];
        tv.x += w * x.x; tv.y += w * x.y; tv.z += w * x.z; tv.w += w * x.w;
    }
    float di = dinv[g];
    float4 z = {di * tv.x, di * tv.y, di * tv.z, di * tv.w};
    const float* Wk = Wl + (size_t)k * 1024;
    float4 acc;
    if (first) {
        acc = *(const float4*)&bias[4 * q];
        float4 hq = *(const float4*)&hin[(size_t)g * 32 + 4 * q];
        mm_acc(acc, hq, Wl, q);
    } else {
        acc = *(const float4*)&outacc[(size_t)g * 32 + 4 * q];
    }
    mm_acc(acc, z, Wk, q);
    if (!last) {
        float4 vo = {di * z.x, di * z.y, di * z.z, di * z.w};
        *(float4*)&vout[(size_t)g * 32 + 4 * q] = vo;
        *(float4*)&outacc[(size_t)g * 32 + 4 * q] = acc;
    } else {
        float4 hv = {LRELU(acc.x), LRELU(acc.y), LRELU(acc.z), LRELU(acc.w)};
        if (!readout) {
            *(float4*)&hout[(size_t)g * 32 + 4 * q] = hv;
            float4 vo = {di * hv.x, di * hv.y, di * hv.z, di * hv.w};
            *(float4*)&vout[(size_t)g * 32 + 4 * q] = vo;
        } else {
            const float4 w4 = *(const float4*)&Wout[4 * q];
            float v = hv.x * w4.x + hv.y * w4.y + hv.z * w4.z + hv.w * w4.w;
            v += __shfl_xor(v, 4, 8);
            v += __shfl_xor(v, 2, 8);
            v += __shfl_xor(v, 1, 8);
            if (q == 0) yout[g] = v + bout[0];
        }
    }
}

// ---- segmented mean over sorted batch: one block per graph ----
__global__ void k_segmean(const float* __restrict__ y, const int* __restrict__ batch,
                          float* __restrict__ out, int N) {
    int b = blockIdx.x;
    __shared__ int slo, shi;
    if (threadIdx.x == 0) {
        int lo = 0, hi = N;
        while (lo < hi) { int m = (lo + hi) >> 1; if (batch[m] < b) lo = m + 1; else hi = m; }
        slo = lo;
        hi = N;
        while (lo < hi) { int m = (lo + hi) >> 1; if (batch[m] < b + 1) lo = m + 1; else hi = m; }
        shi = lo;
    }
    __syncthreads();
    int lo = slo, hi = shi;
    float sum = 0.f;
    for (int i = lo + threadIdx.x; i < hi; i += blockDim.x) sum += y[i];
    __shared__ float sm[256];
    sm[threadIdx.x] = sum;
    __syncthreads();
    for (int o = 128; o; o >>= 1) {
        if (threadIdx.x < o) sm[threadIdx.x] += sm[threadIdx.x + o];
        __syncthreads();
    }
    if (threadIdx.x == 0) out[b] = sm[0] / fmaxf((float)(hi - lo), 1.0f);
}

static inline size_t algn(size_t x) { return (x + 255) & ~(size_t)255; }

extern "C" void kernel_launch(void* const* d_in, const int* in_sizes, int n_in,
                              void* d_out, int out_size, void* d_ws, size_t ws_size,
                              hipStream_t stream) {
    const float* state  = (const float*)d_in[0];
    const float* action = (const float*)d_in[1];
    const int*   eidx   = (const int*)d_in[2];
    const float* eattr  = (const float*)d_in[3];
    const int*   batch  = (const int*)d_in[4];
    const float* Win    = (const float*)d_in[5];
    const float* bin    = (const float*)d_in[6];
    const float* Wtaps  = (const float*)d_in[7];
    const float* bgnn   = (const float*)d_in[8];
    const float* Wout   = (const float*)d_in[9];
    const float* bout   = (const float*)d_in[10];
    float* out = (float*)d_out;

    const int N = in_sizes[0] / 8;       // SD=8
    const int E = in_sizes[3];
    const int B = out_size;
    const int K = 4, L = 2;
    const int NBK = (N + 127) >> BSH;

    const int* row = eidx;
    const int* col = eidx + E;

    // ---- workspace layout ----
    char* base = (char*)d_ws;
    int* ghist = (int*)base;                    // MAXBK, zeroed
    int* gcur  = ghist + MAXBK;                 // MAXBK, zeroed (overwritten by bscan)
    size_t zbytes = (size_t)(2 * MAXBK) * 4;
    char* p = base + algn(zbytes);
    int*   bbase  = (int*)p;  p += algn((size_t)(MAXBK + 1) * 4);
    int*   rowptr = (int*)p;  p += algn((size_t)(N + 1) * 4);
    float* dinv   = (float*)p; p += algn((size_t)N * 4);
    int2*  pairs  = (int2*)p;  p += algn((size_t)E * 8);
    size_t hvbytes = (size_t)2 * N * C * 4;
    if ((size_t)E * 8 > hvbytes) hvbytes = (size_t)E * 8;   // tmp aliases h+vh
    float* h      = (float*)p;
    float* vh     = h + (size_t)N * C;
    int2*  tmp    = (int2*)p;  p += algn(hvbytes);
    float* vA     = (float*)p; p += algn((size_t)N * C * 4);
    float* vB     = (float*)p; p += algn((size_t)N * C * 4);
    float* outacc = (float*)p; p += algn((size_t)N * C * 4);
    float* yv     = (float*)p; p += algn((size_t)N * 4);
    (void)ws_size; (void)n_in;

    const int BT = 256;
    const int gNC = ((size_t)N * 32 + BT - 1) / BT;
    const int gN8 = ((size_t)N * 8 + BT - 1) / BT;

    hipMemsetAsync(d_ws, 0, zbytes, stream);

    k_bhist<<<256, BT, 0, stream>>>(col, ghist, E);
    k_bscan<<<1, 1024, 0, stream>>>(ghist, bbase, gcur, NBK, E);
    k_part<<<512, BT, 0, stream>>>(row, col, eattr, gcur, tmp, E);
    k_build<<<NBK, BT, 0, stream>>>(bbase, tmp, rowptr, dinv, pairs, N, E);

    k_inmlp<<<gNC, BT, 0, stream>>>(state, action, Win, bin, dinv, h, vh, N);

    for (int l = 0; l < L; ++l) {
        const float* Wl = Wtaps + (size_t)l * (K + 1) * 32 * 32;
        const float* bl = bgnn + (size_t)l * 32;
        const float* vin = vh;
        for (int k = 1; k <= K; ++k) {
            int first = (k == 1);
            int last  = (k == K);
            int rdout = last && (l == L - 1);
            float* vout = last ? vh : ((k & 1) ? vA : vB);
            k_tap4<<<gN8, BT, 0, stream>>>(rowptr, pairs, vin, h, dinv,
                                           outacc, vout, h, yv,
                                           Wl, k, bl, Wout, bout,
                                           N, first, last, rdout);
            vin = vout;
        }
    }

    k_segmean<<<B, 256, 0, stream>>>(yv, batch, out, N);
}

// Round 5
// 586.507 us; speedup vs baseline: 3.7238x; 1.1845x over previous
//
#include <hip/hip_runtime.h>

#define LRELU(x) ((x) > 0.f ? (x) : 0.01f * (x))

constexpr int C = 32;
constexpr int BSH = 8;            // 256 dst-nodes per bucket
constexpr int MAXBK = 512;        // max buckets (N <= 131072)

// ---- bf16 pack/unpack helpers ----
__device__ __forceinline__ unsigned pk_bf16(float a, float b) {
    unsigned ua = __float_as_uint(a), ub = __float_as_uint(b);
    unsigned ra = (ua + 0x7fffu + ((ua >> 16) & 1u)) >> 16;
    unsigned rb = (ub + 0x7fffu + ((ub >> 16) & 1u)) & 0xffff0000u;
    return ra | rb;
}
__device__ __forceinline__ float lo_bf16(unsigned w) { return __uint_as_float(w << 16); }
__device__ __forceinline__ float hi_bf16(unsigned w) { return __uint_as_float(w & 0xffff0000u); }

// ---- bucket histogram (LDS-privatized) ----
__global__ void k_bhist(const int* __restrict__ col, int* __restrict__ ghist, int E) {
    __shared__ int lh[MAXBK];
    for (int i = threadIdx.x; i < MAXBK; i += blockDim.x) lh[i] = 0;
    __syncthreads();
    int chunk = (E + gridDim.x - 1) / gridDim.x;
    int c0 = blockIdx.x * chunk, c1 = min(E, c0 + chunk);
    for (int e = c0 + threadIdx.x; e < c1; e += blockDim.x)
        atomicAdd(&lh[col[e] >> BSH], 1);
    __syncthreads();
    for (int i = threadIdx.x; i < MAXBK; i += blockDim.x) {
        int v = lh[i];
        if (v) atomicAdd(&ghist[i], v);
    }
}

// ---- exclusive scan of bucket counts -> bbase, gcur ----
__global__ void k_bscan(const int* __restrict__ ghist, int* __restrict__ bbase,
                        int* __restrict__ gcur, int nbk, int E) {
    __shared__ int sm[MAXBK];
    int tid = threadIdx.x;
    int v = (tid < nbk) ? ghist[tid] : 0;
    sm[tid] = v;
    __syncthreads();
    for (int off = 1; off < MAXBK; off <<= 1) {
        int t = (tid >= off) ? sm[tid - off] : 0;
        __syncthreads();
        sm[tid] += t;
        __syncthreads();
    }
    if (tid < nbk) {
        int excl = sm[tid] - v;
        bbase[tid] = excl;
        gcur[tid] = excl;
    }
    if (tid == 0) bbase[nbk] = E;
}

// ---- partition edges into buckets; per-wg claimed contiguous runs ----
// tmp entry: { src | (dstLow8 << 17), ea_bits }
__global__ void k_part(const int* __restrict__ row, const int* __restrict__ col,
                       const float* __restrict__ ea, int* __restrict__ gcur,
                       int2* __restrict__ tmp, int E) {
    __shared__ int lcnt[MAXBK];
    __shared__ int lbase[MAXBK];
    __shared__ int lcur[MAXBK];
    for (int i = threadIdx.x; i < MAXBK; i += blockDim.x) { lcnt[i] = 0; lcur[i] = 0; }
    __syncthreads();
    int chunk = (E + gridDim.x - 1) / gridDim.x;
    int c0 = blockIdx.x * chunk, c1 = min(E, c0 + chunk);
    for (int e = c0 + threadIdx.x; e < c1; e += blockDim.x)
        atomicAdd(&lcnt[col[e] >> BSH], 1);
    __syncthreads();
    for (int b = threadIdx.x; b < MAXBK; b += blockDim.x) {
        int c = lcnt[b];
        lbase[b] = c ? atomicAdd(&gcur[b], c) : 0;
    }
    __syncthreads();
    for (int e = c0 + threadIdx.x; e < c1; e += blockDim.x) {
        int cc = col[e];
        int b = cc >> BSH;
        int r = atomicAdd(&lcur[b], 1);
        tmp[lbase[b] + r] = make_int2(row[e] | ((cc & 255) << 17), __float_as_int(ea[e]));
    }
}

// ---- per-bucket: node counts + deg (LDS), scan -> rowptr/dinv, scatter to CSR ----
__global__ void k_build(const int* __restrict__ bbase, const int2* __restrict__ tmp,
                        int* __restrict__ rowptr, float* __restrict__ dinv,
                        int2* __restrict__ pairs, int N, int E) {
    __shared__ int ncnt[256], noff[256], ncur[256], scn[256];
    __shared__ float ndeg[256];
    int tid = threadIdx.x;
    int bg = blockIdx.x;
    int node0 = bg << BSH;
    int s = bbase[bg], e = bbase[bg + 1];
    ncnt[tid] = 0; ncur[tid] = 0; ndeg[tid] = 0.f;
    __syncthreads();
    for (int p = s + tid; p < e; p += blockDim.x) {
        int2 u = tmp[p];
        int nl = (u.x >> 17) & 255;
        atomicAdd(&ncnt[nl], 1);
        atomicAdd(&ndeg[nl], __int_as_float(u.y));
    }
    __syncthreads();
    int v = ncnt[tid];
    scn[tid] = v;
    __syncthreads();
    for (int off = 1; off < 256; off <<= 1) {
        int t = (tid >= off) ? scn[tid - off] : 0;
        __syncthreads();
        scn[tid] += t;
        __syncthreads();
    }
    {
        int excl = scn[tid] - v;
        noff[tid] = excl;
        int node = node0 + tid;
        if (node < N) {
            rowptr[node] = s + excl;
            float d = ndeg[tid];
            dinv[node] = d > 0.f ? rsqrtf(fmaxf(d, 1e-12f)) : 0.f;
        }
    }
    if (bg == gridDim.x - 1 && tid == 0) rowptr[N] = E;
    __syncthreads();
    for (int p = s + tid; p < e; p += blockDim.x) {
        int2 u = tmp[p];
        int nl = (u.x >> 17) & 255;
        int r = atomicAdd(&ncur[nl], 1);
        pairs[s + noff[nl] + r] = make_int2(u.x & 0x1FFFF, u.y);
    }
}

// ---- read-in MLP: h = lrelu([state,action]@W_in+b_in); v = bf16(dinv*h) ----
__global__ void k_inmlp(const float* __restrict__ state, const float* __restrict__ action,
                        const float* __restrict__ Win, const float* __restrict__ bin,
                        const float* __restrict__ dinv,
                        float* __restrict__ h, unsigned* __restrict__ v, int N) {
    int t = blockIdx.x * blockDim.x + threadIdx.x;
    int i = t >> 5, c = t & 31;
    if (i >= N) return;
    float acc = bin[c];
#pragma unroll
    for (int d = 0; d < 8; ++d) acc += state[i * 8 + d] * Win[d * 32 + c];
#pragma unroll
    for (int d = 0; d < 2; ++d) acc += action[i * 2 + d] * Win[(8 + d) * 32 + c];
    float hv = LRELU(acc);
    h[i * 32 + c] = hv;
    float vv = dinv[i] * hv;
    float other = __shfl_xor(vv, 1, 32);
    if ((c & 1) == 0) v[(size_t)i * 16 + (c >> 1)] = pk_bf16(vv, other);
}

// acc(4 cols) += z(row, spread over 8 lanes as float4) @ W(32x32), cols 4q..4q+3
__device__ __forceinline__ void mm_acc(float4& acc, float4 zq,
                                       const float* __restrict__ W, int q) {
#pragma unroll
    for (int a = 0; a < 8; ++a) {
        float z0 = __shfl(zq.x, a, 8), z1 = __shfl(zq.y, a, 8);
        float z2 = __shfl(zq.z, a, 8), z3 = __shfl(zq.w, a, 8);
        const float4 w0 = *(const float4*)&W[(4 * a + 0) * 32 + 4 * q];
        const float4 w1 = *(const float4*)&W[(4 * a + 1) * 32 + 4 * q];
        const float4 w2 = *(const float4*)&W[(4 * a + 2) * 32 + 4 * q];
        const float4 w3 = *(const float4*)&W[(4 * a + 3) * 32 + 4 * q];
        acc.x += z0 * w0.x + z1 * w1.x + z2 * w2.x + z3 * w3.x;
        acc.y += z0 * w0.y + z1 * w1.y + z2 * w2.y + z3 * w3.y;
        acc.z += z0 * w0.z + z1 * w1.z + z2 * w2.z + z3 * w3.z;
        acc.w += z0 * w0.w + z1 * w1.w + z2 * w2.w + z3 * w3.w;
    }
}

// ---- fused tap in v-space; 8 lanes per node; v table bf16-packed (64B rows) ----
__global__ void k_tap4(const int* __restrict__ rowptr, const int2* __restrict__ pairs,
                       const uint2* __restrict__ vin, const float* __restrict__ hin,
                       const float* __restrict__ dinv,
                       float* __restrict__ outacc, uint2* __restrict__ vout,
                       float* __restrict__ hout, float* __restrict__ yout,
                       const float* __restrict__ Wl, int k, const float* __restrict__ bias,
                       const float* __restrict__ Wout, const float* __restrict__ bout,
                       int N, int first, int last, int readout) {
    int t = blockIdx.x * blockDim.x + threadIdx.x;
    int g = t >> 3, q = t & 7;
    if (g >= N) return;
    int s = rowptr[g], e = rowptr[g + 1];
    float4 tv = {0.f, 0.f, 0.f, 0.f};
#pragma unroll 4
    for (int p = s; p < e; ++p) {
        int2 pr = pairs[p];
        float w = __int_as_float(pr.y);
        uint2 x = vin[((size_t)pr.x << 3) + q];
        tv.x += w * lo_bf16(x.x); tv.y += w * hi_bf16(x.x);
        tv.z += w * lo_bf16(x.y); tv.w += w * hi_bf16(x.y);
    }
    float di = dinv[g];
    float4 z = {di * tv.x, di * tv.y, di * tv.z, di * tv.w};
    const float* Wk = Wl + (size_t)k * 1024;
    float4 acc;
    if (first) {
        acc = *(const float4*)&bias[4 * q];
        float4 hq = *(const float4*)&hin[(size_t)g * 32 + 4 * q];
        mm_acc(acc, hq, Wl, q);
    } else {
        acc = *(const float4*)&outacc[(size_t)g * 32 + 4 * q];
    }
    mm_acc(acc, z, Wk, q);
    if (!last) {
        *(float4*)&outacc[(size_t)g * 32 + 4 * q] = acc;
        vout[((size_t)g << 3) + q] = make_uint2(pk_bf16(di * z.x, di * z.y),
                                                pk_bf16(di * z.z, di * z.w));
    } else {
        float4 hv = {LRELU(acc.x), LRELU(acc.y), LRELU(acc.z), LRELU(acc.w)};
        if (!readout) {
            *(float4*)&hout[(size_t)g * 32 + 4 * q] = hv;
            vout[((size_t)g << 3) + q] = make_uint2(pk_bf16(di * hv.x, di * hv.y),
                                                    pk_bf16(di * hv.z, di * hv.w));
        } else {
            const float4 w4 = *(const float4*)&Wout[4 * q];
            float v = hv.x * w4.x + hv.y * w4.y + hv.z * w4.z + hv.w * w4.w;
            v += __shfl_xor(v, 4, 8);
            v += __shfl_xor(v, 2, 8);
            v += __shfl_xor(v, 1, 8);
            if (q == 0) yout[g] = v + bout[0];
        }
    }
}

// ---- segmented mean over sorted batch: one block per graph ----
__global__ void k_segmean(const float* __restrict__ y, const int* __restrict__ batch,
                          float* __restrict__ out, int N) {
    int b = blockIdx.x;
    __shared__ int slo, shi;
    if (threadIdx.x == 0) {
        int lo = 0, hi = N;
        while (lo < hi) { int m = (lo + hi) >> 1; if (batch[m] < b) lo = m + 1; else hi = m; }
        slo = lo;
        hi = N;
        while (lo < hi) { int m = (lo + hi) >> 1; if (batch[m] < b + 1) lo = m + 1; else hi = m; }
        shi = lo;
    }
    __syncthreads();
    int lo = slo, hi = shi;
    float sum = 0.f;
    for (int i = lo + threadIdx.x; i < hi; i += blockDim.x) sum += y[i];
    __shared__ float sm[256];
    sm[threadIdx.x] = sum;
    __syncthreads();
    for (int o = 128; o; o >>= 1) {
        if (threadIdx.x < o) sm[threadIdx.x] += sm[threadIdx.x + o];
        __syncthreads();
    }
    if (threadIdx.x == 0) out[b] = sm[0] / fmaxf((float)(hi - lo), 1.0f);
}

static inline size_t algn(size_t x) { return (x + 255) & ~(size_t)255; }

extern "C" void kernel_launch(void* const* d_in, const int* in_sizes, int n_in,
                              void* d_out, int out_size, void* d_ws, size_t ws_size,
                              hipStream_t stream) {
    const float* state  = (const float*)d_in[0];
    const float* action = (const float*)d_in[1];
    const int*   eidx   = (const int*)d_in[2];
    const float* eattr  = (const float*)d_in[3];
    const int*   batch  = (const int*)d_in[4];
    const float* Win    = (const float*)d_in[5];
    const float* bin    = (const float*)d_in[6];
    const float* Wtaps  = (const float*)d_in[7];
    const float* bgnn   = (const float*)d_in[8];
    const float* Wout   = (const float*)d_in[9];
    const float* bout   = (const float*)d_in[10];
    float* out = (float*)d_out;

    const int N = in_sizes[0] / 8;       // SD=8
    const int E = in_sizes[3];
    const int B = out_size;
    const int K = 4, L = 2;
    const int NBK = (N + 255) >> BSH;

    const int* row = eidx;
    const int* col = eidx + E;

    // ---- workspace layout ----
    char* base = (char*)d_ws;
    int* ghist = (int*)base;                    // MAXBK, zeroed
    int* gcur  = ghist + MAXBK;                 // written by bscan
    size_t zbytes = (size_t)MAXBK * 4;
    char* p = base + algn((size_t)2 * MAXBK * 4);
    int*   bbase  = (int*)p;  p += algn((size_t)(MAXBK + 1) * 4);
    int*   rowptr = (int*)p;  p += algn((size_t)(N + 1) * 4);
    float* dinv   = (float*)p; p += algn((size_t)N * 4);
    int2*  pairs  = (int2*)p;  p += algn((size_t)E * 8);
    // region: h (f32, N*32) | vh (bf16, N*16 u32) | vA (bf16) — aliased by tmp
    size_t region = (size_t)N * (128 + 64 + 64);
    if ((size_t)E * 8 > region) region = (size_t)E * 8;
    float*    h   = (float*)p;
    unsigned* vh  = (unsigned*)(p + (size_t)N * 128);
    unsigned* vA  = (unsigned*)(p + (size_t)N * 192);
    int2*     tmp = (int2*)p;  p += algn(region);
    unsigned* vB  = (unsigned*)p; p += algn((size_t)N * 64);
    float* outacc = (float*)p; p += algn((size_t)N * C * 4);
    float* yv     = (float*)p; p += algn((size_t)N * 4);
    (void)ws_size; (void)n_in;

    const int BT = 256;
    const int gNC = ((size_t)N * 32 + BT - 1) / BT;
    const int gN8 = ((size_t)N * 8 + BT - 1) / BT;

    hipMemsetAsync(d_ws, 0, zbytes, stream);

    k_bhist<<<512, BT, 0, stream>>>(col, ghist, E);
    k_bscan<<<1, MAXBK, 0, stream>>>(ghist, bbase, gcur, NBK, E);
    k_part<<<256, 1024, 0, stream>>>(row, col, eattr, gcur, tmp, E);
    k_build<<<NBK, 256, 0, stream>>>(bbase, tmp, rowptr, dinv, pairs, N, E);

    k_inmlp<<<gNC, BT, 0, stream>>>(state, action, Win, bin, dinv, h, vh, N);

    for (int l = 0; l < L; ++l) {
        const float* Wl = Wtaps + (size_t)l * (K + 1) * 32 * 32;
        const float* bl = bgnn + (size_t)l * 32;
        const unsigned* vin = vh;
        for (int k = 1; k <= K; ++k) {
            int first = (k == 1);
            int last  = (k == K);
            int rdout = last && (l == L - 1);
            unsigned* vout = last ? vh : ((k & 1) ? vA : vB);
            k_tap4<<<gN8, BT, 0, stream>>>(rowptr, pairs, (const uint2*)vin, h, dinv,
                                           outacc, (uint2*)vout, h, yv,
                                           Wl, k, bl, Wout, bout,
                                           N, first, last, rdout);
            vin = vout;
        }
    }

    k_segmean<<<B, 256, 0, stream>>>(yv, batch, out, N);
}

// Round 6
// 538.928 us; speedup vs baseline: 4.0525x; 1.0883x over previous
//
#include <hip/hip_runtime.h>

#define LRELU(x) ((x) > 0.f ? (x) : 0.01f * (x))

constexpr int C = 32;
constexpr int BSH = 8;            // 256 dst-nodes per bucket
constexpr int MAXBK = 512;        // max buckets (N <= 131072)

// ---- bf16 pack/unpack helpers ----
__device__ __forceinline__ unsigned pk_bf16(float a, float b) {
    unsigned ua = __float_as_uint(a), ub = __float_as_uint(b);
    unsigned ra = (ua + 0x7fffu + ((ua >> 16) & 1u)) >> 16;
    unsigned rb = (ub + 0x7fffu + ((ub >> 16) & 1u)) & 0xffff0000u;
    return ra | rb;
}
__device__ __forceinline__ float lo_bf16(unsigned w) { return __uint_as_float(w << 16); }
__device__ __forceinline__ float hi_bf16(unsigned w) { return __uint_as_float(w & 0xffff0000u); }

// ---- bucket histogram (LDS-privatized) ----
__global__ void k_bhist(const int* __restrict__ col, int* __restrict__ ghist, int E) {
    __shared__ int lh[MAXBK];
    for (int i = threadIdx.x; i < MAXBK; i += blockDim.x) lh[i] = 0;
    __syncthreads();
    int chunk = (E + gridDim.x - 1) / gridDim.x;
    int c0 = blockIdx.x * chunk, c1 = min(E, c0 + chunk);
    for (int e = c0 + threadIdx.x; e < c1; e += blockDim.x)
        atomicAdd(&lh[col[e] >> BSH], 1);
    __syncthreads();
    for (int i = threadIdx.x; i < MAXBK; i += blockDim.x) {
        int v = lh[i];
        if (v) atomicAdd(&ghist[i], v);
    }
}

// ---- exclusive scan of bucket counts -> bbase, gcur ----
__global__ void k_bscan(const int* __restrict__ ghist, int* __restrict__ bbase,
                        int* __restrict__ gcur, int nbk, int E) {
    __shared__ int sm[MAXBK];
    int tid = threadIdx.x;
    int v = (tid < nbk) ? ghist[tid] : 0;
    sm[tid] = v;
    __syncthreads();
    for (int off = 1; off < MAXBK; off <<= 1) {
        int t = (tid >= off) ? sm[tid - off] : 0;
        __syncthreads();
        sm[tid] += t;
        __syncthreads();
    }
    if (tid < nbk) {
        int excl = sm[tid] - v;
        bbase[tid] = excl;
        gcur[tid] = excl;
    }
    if (tid == 0) bbase[nbk] = E;
}

// ---- partition edges into buckets; per-wg claimed contiguous runs ----
// tmp entry: { src | (dstLow8 << 17), ea_bits }
__global__ void k_part(const int* __restrict__ row, const int* __restrict__ col,
                       const float* __restrict__ ea, int* __restrict__ gcur,
                       int2* __restrict__ tmp, int E) {
    __shared__ int lcnt[MAXBK];
    __shared__ int lbase[MAXBK];
    __shared__ int lcur[MAXBK];
    for (int i = threadIdx.x; i < MAXBK; i += blockDim.x) { lcnt[i] = 0; lcur[i] = 0; }
    __syncthreads();
    int chunk = (E + gridDim.x - 1) / gridDim.x;
    int c0 = blockIdx.x * chunk, c1 = min(E, c0 + chunk);
    for (int e = c0 + threadIdx.x; e < c1; e += blockDim.x)
        atomicAdd(&lcnt[col[e] >> BSH], 1);
    __syncthreads();
    for (int b = threadIdx.x; b < MAXBK; b += blockDim.x) {
        int c = lcnt[b];
        lbase[b] = c ? atomicAdd(&gcur[b], c) : 0;
    }
    __syncthreads();
    for (int e = c0 + threadIdx.x; e < c1; e += blockDim.x) {
        int cc = col[e];
        int b = cc >> BSH;
        int r = atomicAdd(&lcur[b], 1);
        tmp[lbase[b] + r] = make_int2(row[e] | ((cc & 255) << 17), __float_as_int(ea[e]));
    }
}

// ---- per-bucket CSR build with 4-way src-quartile ordering inside each row ----
__global__ void k_build(const int* __restrict__ bbase, const int2* __restrict__ tmp,
                        int* __restrict__ rowptr, float* __restrict__ dinv,
                        int2* __restrict__ pairs, int N, int E) {
    __shared__ int ncnt[1024], noff[1024], ncur[1024];
    __shared__ int tsum[256];
    __shared__ float ndeg[256];
    int tid = threadIdx.x;          // 256 threads
    int bg = blockIdx.x;
    int node0 = bg << BSH;
    int s = bbase[bg], e = bbase[bg + 1];
    for (int i = tid; i < 1024; i += 256) { ncnt[i] = 0; ncur[i] = 0; }
    ndeg[tid] = 0.f;
    __syncthreads();
    for (int p = s + tid; p < e; p += 256) {
        int2 u = tmp[p];
        int nl = (u.x >> 17) & 255;
        int qt = (u.x & 0x1FFFF) >> 15;        // src quartile (N < 2^17)
        atomicAdd(&ncnt[nl * 4 + qt], 1);
        atomicAdd(&ndeg[nl], __int_as_float(u.y));
    }
    __syncthreads();
    int c0 = ncnt[4 * tid], c1 = ncnt[4 * tid + 1];
    int c2 = ncnt[4 * tid + 2], c3 = ncnt[4 * tid + 3];
    int mysum = c0 + c1 + c2 + c3;
    tsum[tid] = mysum;
    __syncthreads();
    for (int off = 1; off < 256; off <<= 1) {
        int t = (tid >= off) ? tsum[tid - off] : 0;
        __syncthreads();
        tsum[tid] += t;
        __syncthreads();
    }
    {
        int base = tsum[tid] - mysum;          // exclusive over nodes
        noff[4 * tid + 0] = base;
        noff[4 * tid + 1] = base + c0;
        noff[4 * tid + 2] = base + c0 + c1;
        noff[4 * tid + 3] = base + c0 + c1 + c2;
        int node = node0 + tid;
        if (node < N) {
            rowptr[node] = s + base;
            float d = ndeg[tid];
            dinv[node] = d > 0.f ? rsqrtf(fmaxf(d, 1e-12f)) : 0.f;
        }
    }
    if (bg == gridDim.x - 1 && tid == 0) rowptr[N] = E;
    __syncthreads();
    for (int p = s + tid; p < e; p += 256) {
        int2 u = tmp[p];
        int nl = (u.x >> 17) & 255;
        int src = u.x & 0x1FFFF;
        int qt = src >> 15;
        int r = atomicAdd(&ncur[nl * 4 + qt], 1);
        pairs[s + noff[nl * 4 + qt] + r] = make_int2(src, u.y);
    }
}

// ---- read-in MLP: h = lrelu([state,action]@W_in+b_in); v = bf16(dinv*h) ----
__global__ void k_inmlp(const float* __restrict__ state, const float* __restrict__ action,
                        const float* __restrict__ Win, const float* __restrict__ bin,
                        const float* __restrict__ dinv,
                        float* __restrict__ h, unsigned* __restrict__ v, int N) {
    int t = blockIdx.x * blockDim.x + threadIdx.x;
    int i = t >> 5, c = t & 31;
    if (i >= N) return;
    float acc = bin[c];
#pragma unroll
    for (int d = 0; d < 8; ++d) acc += state[i * 8 + d] * Win[d * 32 + c];
#pragma unroll
    for (int d = 0; d < 2; ++d) acc += action[i * 2 + d] * Win[(8 + d) * 32 + c];
    float hv = LRELU(acc);
    h[i * 32 + c] = hv;
    float vv = dinv[i] * hv;
    float other = __shfl_xor(vv, 1, 32);
    if ((c & 1) == 0) v[(size_t)i * 16 + (c >> 1)] = pk_bf16(vv, other);
}

// acc(4 cols) += z(row, spread over 8 lanes as float4) @ W(32x32), cols 4q..4q+3
__device__ __forceinline__ void mm_acc(float4& acc, float4 zq,
                                       const float* __restrict__ W, int q) {
#pragma unroll
    for (int a = 0; a < 8; ++a) {
        float z0 = __shfl(zq.x, a, 8), z1 = __shfl(zq.y, a, 8);
        float z2 = __shfl(zq.z, a, 8), z3 = __shfl(zq.w, a, 8);
        const float4 w0 = *(const float4*)&W[(4 * a + 0) * 32 + 4 * q];
        const float4 w1 = *(const float4*)&W[(4 * a + 1) * 32 + 4 * q];
        const float4 w2 = *(const float4*)&W[(4 * a + 2) * 32 + 4 * q];
        const float4 w3 = *(const float4*)&W[(4 * a + 3) * 32 + 4 * q];
        acc.x += z0 * w0.x + z1 * w1.x + z2 * w2.x + z3 * w3.x;
        acc.y += z0 * w0.y + z1 * w1.y + z2 * w2.y + z3 * w3.y;
        acc.z += z0 * w0.z + z1 * w1.z + z2 * w2.z + z3 * w3.z;
        acc.w += z0 * w0.w + z1 * w1.w + z2 * w2.w + z3 * w3.w;
    }
}

__device__ __forceinline__ void edge_acc(float4& tv, float w, uint2 x) {
    tv.x += w * lo_bf16(x.x); tv.y += w * hi_bf16(x.x);
    tv.z += w * lo_bf16(x.y); tv.w += w * hi_bf16(x.y);
}

// ---- fused tap in v-space; 8 lanes per node; bf16 v-table; pipelined gather ----
__global__ void k_tap4(const int* __restrict__ rowptr, const int2* __restrict__ pairs,
                       const uint2* __restrict__ vin, const float* __restrict__ hin,
                       const float* __restrict__ dinv,
                       float* __restrict__ outacc, uint2* __restrict__ vout,
                       float* __restrict__ hout, float* __restrict__ yout,
                       const float* __restrict__ Wl, int k, const float* __restrict__ bias,
                       const float* __restrict__ Wout, const float* __restrict__ bout,
                       int N, int first, int last, int readout) {
    int t = blockIdx.x * blockDim.x + threadIdx.x;
    int g = t >> 3, q = t & 7;
    if (g >= N) return;
    int s = rowptr[g], e = rowptr[g + 1];
    float4 tv = {0.f, 0.f, 0.f, 0.f};
    int p = s;
    if ((p & 1) && p < e) {                 // peel to 16B-aligned pair index
        int2 pr = pairs[p];
        uint2 x = vin[((size_t)(unsigned)pr.x << 3) + q];
        edge_acc(tv, __int_as_float(pr.y), x);
        ++p;
    }
#pragma unroll 2
    for (; p + 4 <= e; p += 4) {            // 4 edges: 2x int4 pair-loads, 4 gathers
        int4 pa = *(const int4*)&pairs[p];
        int4 pb = *(const int4*)&pairs[p + 2];
        uint2 x0 = vin[((size_t)(unsigned)pa.x << 3) + q];
        uint2 x1 = vin[((size_t)(unsigned)pa.z << 3) + q];
        uint2 x2 = vin[((size_t)(unsigned)pb.x << 3) + q];
        uint2 x3 = vin[((size_t)(unsigned)pb.z << 3) + q];
        edge_acc(tv, __int_as_float(pa.y), x0);
        edge_acc(tv, __int_as_float(pa.w), x1);
        edge_acc(tv, __int_as_float(pb.y), x2);
        edge_acc(tv, __int_as_float(pb.w), x3);
    }
    for (; p < e; ++p) {                    // tail
        int2 pr = pairs[p];
        uint2 x = vin[((size_t)(unsigned)pr.x << 3) + q];
        edge_acc(tv, __int_as_float(pr.y), x);
    }
    float di = dinv[g];
    float4 z = {di * tv.x, di * tv.y, di * tv.z, di * tv.w};
    const float* Wk = Wl + (size_t)k * 1024;
    float4 acc;
    if (first) {
        acc = *(const float4*)&bias[4 * q];
        float4 hq = *(const float4*)&hin[(size_t)g * 32 + 4 * q];
        mm_acc(acc, hq, Wl, q);
    } else {
        acc = *(const float4*)&outacc[(size_t)g * 32 + 4 * q];
    }
    mm_acc(acc, z, Wk, q);
    if (!last) {
        *(float4*)&outacc[(size_t)g * 32 + 4 * q] = acc;
        vout[((size_t)g << 3) + q] = make_uint2(pk_bf16(di * z.x, di * z.y),
                                                pk_bf16(di * z.z, di * z.w));
    } else {
        float4 hv = {LRELU(acc.x), LRELU(acc.y), LRELU(acc.z), LRELU(acc.w)};
        if (!readout) {
            *(float4*)&hout[(size_t)g * 32 + 4 * q] = hv;
            vout[((size_t)g << 3) + q] = make_uint2(pk_bf16(di * hv.x, di * hv.y),
                                                    pk_bf16(di * hv.z, di * hv.w));
        } else {
            const float4 w4 = *(const float4*)&Wout[4 * q];
            float v = hv.x * w4.x + hv.y * w4.y + hv.z * w4.z + hv.w * w4.w;
            v += __shfl_xor(v, 4, 8);
            v += __shfl_xor(v, 2, 8);
            v += __shfl_xor(v, 1, 8);
            if (q == 0) yout[g] = v + bout[0];
        }
    }
}

// ---- segmented mean over sorted batch: one block per graph ----
__global__ void k_segmean(const float* __restrict__ y, const int* __restrict__ batch,
                          float* __restrict__ out, int N) {
    int b = blockIdx.x;
    __shared__ int slo, shi;
    if (threadIdx.x == 0) {
        int lo = 0, hi = N;
        while (lo < hi) { int m = (lo + hi) >> 1; if (batch[m] < b) lo = m + 1; else hi = m; }
        slo = lo;
        hi = N;
        while (lo < hi) { int m = (lo + hi) >> 1; if (batch[m] < b + 1) lo = m + 1; else hi = m; }
        shi = lo;
    }
    __syncthreads();
    int lo = slo, hi = shi;
    float sum = 0.f;
    for (int i = lo + threadIdx.x; i < hi; i += blockDim.x) sum += y[i];
    __shared__ float sm[256];
    sm[threadIdx.x] = sum;
    __syncthreads();
    for (int o = 128; o; o >>= 1) {
        if (threadIdx.x < o) sm[threadIdx.x] += sm[threadIdx.x + o];
        __syncthreads();
    }
    if (threadIdx.x == 0) out[b] = sm[0] / fmaxf((float)(hi - lo), 1.0f);
}

static inline size_t algn(size_t x) { return (x + 255) & ~(size_t)255; }

extern "C" void kernel_launch(void* const* d_in, const int* in_sizes, int n_in,
                              void* d_out, int out_size, void* d_ws, size_t ws_size,
                              hipStream_t stream) {
    const float* state  = (const float*)d_in[0];
    const float* action = (const float*)d_in[1];
    const int*   eidx   = (const int*)d_in[2];
    const float* eattr  = (const float*)d_in[3];
    const int*   batch  = (const int*)d_in[4];
    const float* Win    = (const float*)d_in[5];
    const float* bin    = (const float*)d_in[6];
    const float* Wtaps  = (const float*)d_in[7];
    const float* bgnn   = (const float*)d_in[8];
    const float* Wout   = (const float*)d_in[9];
    const float* bout   = (const float*)d_in[10];
    float* out = (float*)d_out;

    const int N = in_sizes[0] / 8;       // SD=8
    const int E = in_sizes[3];
    const int B = out_size;
    const int K = 4, L = 2;
    const int NBK = (N + 255) >> BSH;

    const int* row = eidx;
    const int* col = eidx + E;

    // ---- workspace layout ----
    char* base = (char*)d_ws;
    int* ghist = (int*)base;                    // MAXBK, zeroed
    int* gcur  = ghist + MAXBK;                 // written by bscan
    size_t zbytes = (size_t)MAXBK * 4;
    char* p = base + algn((size_t)2 * MAXBK * 4);
    int*   bbase  = (int*)p;  p += algn((size_t)(MAXBK + 1) * 4);
    int*   rowptr = (int*)p;  p += algn((size_t)(N + 1) * 4);
    float* dinv   = (float*)p; p += algn((size_t)N * 4);
    int2*  pairs  = (int2*)p;  p += algn((size_t)E * 8);
    // region: h (f32, N*32) | vh (bf16, N*16 u32) | vA (bf16) — aliased by tmp
    size_t region = (size_t)N * (128 + 64 + 64);
    if ((size_t)E * 8 > region) region = (size_t)E * 8;
    float*    h   = (float*)p;
    unsigned* vh  = (unsigned*)(p + (size_t)N * 128);
    unsigned* vA  = (unsigned*)(p + (size_t)N * 192);
    int2*     tmp = (int2*)p;  p += algn(region);
    unsigned* vB  = (unsigned*)p; p += algn((size_t)N * 64);
    float* outacc = (float*)p; p += algn((size_t)N * C * 4);
    float* yv     = (float*)p; p += algn((size_t)N * 4);
    (void)ws_size; (void)n_in;

    const int BT = 256;
    const int gNC = ((size_t)N * 32 + BT - 1) / BT;
    const int gN8 = ((size_t)N * 8 + BT - 1) / BT;

    hipMemsetAsync(d_ws, 0, zbytes, stream);

    k_bhist<<<512, BT, 0, stream>>>(col, ghist, E);
    k_bscan<<<1, MAXBK, 0, stream>>>(ghist, bbase, gcur, NBK, E);
    k_part<<<256, 1024, 0, stream>>>(row, col, eattr, gcur, tmp, E);
    k_build<<<NBK, 256, 0, stream>>>(bbase, tmp, rowptr, dinv, pairs, N, E);

    k_inmlp<<<gNC, BT, 0, stream>>>(state, action, Win, bin, dinv, h, vh, N);

    for (int l = 0; l < L; ++l) {
        const float* Wl = Wtaps + (size_t)l * (K + 1) * 32 * 32;
        const float* bl = bgnn + (size_t)l * 32;
        const unsigned* vin = vh;
        for (int k = 1; k <= K; ++k) {
            int first = (k == 1);
            int last  = (k == K);
            int rdout = last && (l == L - 1);
            unsigned* vout = last ? vh : ((k & 1) ? vA : vB);
            k_tap4<<<gN8, BT, 0, stream>>>(rowptr, pairs, (const uint2*)vin, h, dinv,
                                           outacc, (uint2*)vout, h, yv,
                                           Wl, k, bl, Wout, bout,
                                           N, first, last, rdout);
            vin = vout;
        }
    }

    k_segmean<<<B, 256, 0, stream>>>(yv, batch, out, N);
}